// Round 1
// baseline (329.887 us; speedup 1.0000x reference)
//
#include <hip/hip_runtime.h>
#include <math.h>

#define B_ 16
#define F_ 512
#define T_ 4000
#define D_ 100    // pooled length
#define E_ 256    // embed dim
#define ROWS (B_*F_)   // 8192

// ---------------- K1: adaptive avg pool (window=40) + per-row mean ----------
__global__ __launch_bounds__(256) void k_pool(const float* __restrict__ x,
                                              float* __restrict__ pooled,
                                              float* __restrict__ xmean) {
    __shared__ float buf[T_];
    __shared__ float wsum[128];
    const int row = blockIdx.x;
    const int tid = threadIdx.x;
    const float4* xr = (const float4*)(x + (size_t)row * T_);
    float4* buf4 = (float4*)buf;
    for (int i = tid; i < T_/4; i += 256) buf4[i] = xr[i];
    __syncthreads();
    if (tid < D_) {
        float s = 0.f;
        const float* p = buf + tid * 40;
        #pragma unroll
        for (int j = 0; j < 40; ++j) s += p[j];
        pooled[(size_t)row * D_ + tid] = s * (1.0f/40.0f);
        wsum[tid] = s;
    }
    __syncthreads();
    if (tid == 0) {
        float s = 0.f;
        #pragma unroll
        for (int j = 0; j < D_; ++j) s += wsum[j];
        xmean[row] = s * (1.0f/(float)T_);
    }
}

// ---------------- K2: KQ[m, 0:256]=key, KQ[m, 256:512]=query ----------------
// C[m,n] = sum_k pooled[m,k] * W[n,k] + b[n], 64x64 tile, K=100 staged whole.
__global__ __launch_bounds__(256) void k_kq(const float* __restrict__ pooled,
                                            const float* __restrict__ Wk,
                                            const float* __restrict__ bk,
                                            const float* __restrict__ Wq,
                                            const float* __restrict__ bq,
                                            float* __restrict__ KQ) {
    __shared__ float As[D_][65];   // k-major, +1 pad: conflict-free transpose writes
    __shared__ float Bs[D_][65];
    const int m0 = blockIdx.x * 64;
    const int n0 = blockIdx.y * 64;
    const int tid = threadIdx.x;

    const float* Ab = pooled + (size_t)m0 * D_;          // contiguous 6400 floats
    for (int i = tid; i < 64 * D_; i += 256) {
        int r = i / D_, k = i - r * D_;
        As[k][r] = Ab[i];
    }
    const float* Wb = (n0 < E_) ? (Wk + (size_t)n0 * D_) : (Wq + (size_t)(n0 - E_) * D_);
    for (int i = tid; i < 64 * D_; i += 256) {
        int r = i / D_, k = i - r * D_;
        Bs[k][r] = Wb[i];
    }
    __syncthreads();

    const int tm = (tid >> 4) * 4;
    const int tn = (tid & 15) * 4;
    float acc[4][4] = {};
    for (int k = 0; k < D_; ++k) {
        float a[4], b[4];
        #pragma unroll
        for (int i = 0; i < 4; ++i) a[i] = As[k][tm + i];
        #pragma unroll
        for (int j = 0; j < 4; ++j) b[j] = Bs[k][tn + j];
        #pragma unroll
        for (int i = 0; i < 4; ++i)
            #pragma unroll
            for (int j = 0; j < 4; ++j)
                acc[i][j] = fmaf(a[i], b[j], acc[i][j]);
    }
    #pragma unroll
    for (int i = 0; i < 4; ++i)
        #pragma unroll
        for (int j = 0; j < 4; ++j) {
            int n = n0 + tn + j;
            float bias = (n < E_) ? bk[n] : bq[n - E_];
            KQ[(size_t)(m0 + tm + i) * 512 + n] = acc[i][j] + bias;
        }
}

// ---------------- K3: per-batch S = key @ query^T, scaled by 1/16 -----------
__global__ __launch_bounds__(256) void k_scores(const float* __restrict__ KQ,
                                                float* __restrict__ S) {
    __shared__ float As[64][68];   // +4 pad keeps 16B alignment for float4 reads
    __shared__ float Bs[64][68];
    const int b  = blockIdx.z;
    const int f0 = blockIdx.x * 64;
    const int g0 = blockIdx.y * 64;
    const float* Ab = KQ + ((size_t)b * F_ + f0) * 512;         // key cols 0..255
    const float* Bb = KQ + ((size_t)b * F_ + g0) * 512 + E_;    // query cols 256..511
    const int tid = threadIdx.x;
    const int tm = (tid >> 4) * 4;
    const int tn = (tid & 15) * 4;
    float acc[4][4] = {};
    for (int ks = 0; ks < E_; ks += 64) {
        for (int i = tid; i < 64 * 64; i += 256) {
            int r = i >> 6, kk = i & 63;      // consecutive tid -> consecutive kk: coalesced global
            As[kk][r] = Ab[(size_t)r * 512 + ks + kk];
            Bs[kk][r] = Bb[(size_t)r * 512 + ks + kk];
        }
        __syncthreads();
        #pragma unroll 16
        for (int k = 0; k < 64; ++k) {
            float4 a4 = *(const float4*)(&As[k][tm]);
            float4 b4 = *(const float4*)(&Bs[k][tn]);
            float a[4] = {a4.x, a4.y, a4.z, a4.w};
            float b[4] = {b4.x, b4.y, b4.z, b4.w};
            #pragma unroll
            for (int i = 0; i < 4; ++i)
                #pragma unroll
                for (int j = 0; j < 4; ++j)
                    acc[i][j] = fmaf(a[i], b[j], acc[i][j]);
        }
        __syncthreads();
    }
    float* Sb = S + ((size_t)b * F_ + f0) * 512 + g0;
    #pragma unroll
    for (int i = 0; i < 4; ++i)
        #pragma unroll
        for (int j = 0; j < 4; ++j)
            Sb[(size_t)(tm + i) * 512 + tn + j] = acc[i][j] * (1.0f/16.0f);
}

// ---------------- K4: softmax over g + fw = att @ xmean ---------------------
__global__ __launch_bounds__(256) void k_softmax_fw(const float* __restrict__ S,
                                                    const float* __restrict__ xmean,
                                                    float* __restrict__ fw) {
    __shared__ float r1[256];
    __shared__ float r2[256];
    const int row = blockIdx.x;            // b*512 + f
    const int b = row >> 9;
    const float* Sr = S + (size_t)row * 512;
    const float* xm = xmean + ((size_t)b << 9);
    const int tid = threadIdx.x;
    float v0 = Sr[tid], v1 = Sr[tid + 256];
    r1[tid] = fmaxf(v0, v1);
    __syncthreads();
    for (int s = 128; s > 0; s >>= 1) {
        if (tid < s) r1[tid] = fmaxf(r1[tid], r1[tid + s]);
        __syncthreads();
    }
    float m = r1[0];
    __syncthreads();
    float p0 = expf(v0 - m), p1 = expf(v1 - m);
    r1[tid] = p0 + p1;
    r2[tid] = p0 * xm[tid] + p1 * xm[tid + 256];
    __syncthreads();
    for (int s = 128; s > 0; s >>= 1) {
        if (tid < s) { r1[tid] += r1[tid + s]; r2[tid] += r2[tid + s]; }
        __syncthreads();
    }
    if (tid == 0) fw[row] = r2[0] / r1[0];
}

// ---------------- K5: per-batch min/max normalize ---------------------------
__global__ __launch_bounds__(512) void k_norm(const float* __restrict__ fw,
                                              float* __restrict__ fwn) {
    __shared__ float rmin[512];
    __shared__ float rmax[512];
    const int b = blockIdx.x, tid = threadIdx.x;
    float v = fw[b * F_ + tid];
    rmin[tid] = v; rmax[tid] = v;
    __syncthreads();
    for (int s = 256; s > 0; s >>= 1) {
        if (tid < s) {
            rmin[tid] = fminf(rmin[tid], rmin[tid + s]);
            rmax[tid] = fmaxf(rmax[tid], rmax[tid + s]);
        }
        __syncthreads();
    }
    float mi = rmin[0], ma = rmax[0];
    fwn[b * F_ + tid] = (v - mi) / (ma - mi) + 1e-6f;
}

// ---------------- K6: out = x * fw_n ---------------------------------------
__global__ __launch_bounds__(256) void k_scale(const float* __restrict__ x,
                                               const float* __restrict__ fwn,
                                               float* __restrict__ out) {
    const int row = blockIdx.x;
    const float s = fwn[row];
    const float4* xr = (const float4*)(x + (size_t)row * T_);
    float4* orow = (float4*)(out + (size_t)row * T_);
    for (int i = threadIdx.x; i < T_/4; i += 256) {
        float4 v = xr[i];
        v.x *= s; v.y *= s; v.z *= s; v.w *= s;
        orow[i] = v;
    }
}

extern "C" void kernel_launch(void* const* d_in, const int* in_sizes, int n_in,
                              void* d_out, int out_size, void* d_ws, size_t ws_size,
                              hipStream_t stream) {
    const float* x  = (const float*)d_in[0];
    const float* Wk = (const float*)d_in[1];
    const float* bk = (const float*)d_in[2];
    const float* Wq = (const float*)d_in[3];
    const float* bq = (const float*)d_in[4];
    float* out = (float*)d_out;

    float* ws     = (float*)d_ws;
    float* pooled = ws;                                  // 8192*100
    float* xmean  = pooled + (size_t)ROWS * D_;          // 8192
    float* KQ     = xmean + ROWS;                        // 8192*512
    float* S      = KQ + (size_t)ROWS * 512;             // 16*512*512
    float* fw     = S + (size_t)B_ * F_ * F_;            // 8192
    float* fwn    = fw + ROWS;                           // 8192

    k_pool<<<ROWS, 256, 0, stream>>>(x, pooled, xmean);
    k_kq<<<dim3(ROWS/64, 512/64), 256, 0, stream>>>(pooled, Wk, bk, Wq, bq, KQ);
    k_scores<<<dim3(F_/64, F_/64, B_), 256, 0, stream>>>(KQ, S);
    k_softmax_fw<<<ROWS, 256, 0, stream>>>(S, xmean, fw);
    k_norm<<<B_, 512, 0, stream>>>(fw, fwn);
    k_scale<<<ROWS, 256, 0, stream>>>(x, fwn, out);
}

// Round 2
// 321.053 us; speedup vs baseline: 1.0275x; 1.0275x over previous
//
#include <hip/hip_runtime.h>
#include <math.h>

#define B_ 16
#define F_ 512
#define T_ 4000
#define D_ 100    // pooled length
#define E_ 256    // embed dim
#define ROWS (B_*F_)   // 8192

// ---------------- K1: adaptive avg pool (window=40) + per-row mean ----------
// Register-only: thread t (t<200) loads floats [20t, 20t+20) = half a window,
// pair-combines via shfl_xor(1). No big LDS, no bank conflicts, no serial tail.
__global__ __launch_bounds__(256) void k_pool(const float* __restrict__ x,
                                              float* __restrict__ pooled,
                                              float* __restrict__ xmean) {
    __shared__ float part[4];
    const int row = blockIdx.x;
    const int tid = threadIdx.x;
    float s = 0.f;
    if (tid < 200) {
        // 20*t floats = 80t bytes -> always 16B aligned; row base 16000B aligned.
        const float4* p = (const float4*)(x + (size_t)row * T_ + 20 * tid);
        float4 a0 = p[0], a1 = p[1], a2 = p[2], a3 = p[3], a4 = p[4];
        s  = a0.x + a0.y + a0.z + a0.w;
        s += a1.x + a1.y + a1.z + a1.w;
        s += a2.x + a2.y + a2.z + a2.w;
        s += a3.x + a3.y + a3.z + a3.w;
        s += a4.x + a4.y + a4.z + a4.w;
    }
    // window sum = pair (2w, 2w+1)
    float other = __shfl_xor(s, 1);
    if (tid < 200 && (tid & 1) == 0)
        pooled[(size_t)row * D_ + (tid >> 1)] = (s + other) * (1.0f/40.0f);
    // xmean: full-block sum of s
    float tot = s;
    #pragma unroll
    for (int off = 32; off; off >>= 1) tot += __shfl_xor(tot, off);
    if ((tid & 63) == 0) part[tid >> 6] = tot;
    __syncthreads();
    if (tid == 0)
        xmean[row] = (part[0] + part[1] + part[2] + part[3]) * (1.0f/(float)T_);
}

// ---------------- K2: KQ[m, 0:256]=key, KQ[m, 256:512]=query ----------------
__global__ __launch_bounds__(256) void k_kq(const float* __restrict__ pooled,
                                            const float* __restrict__ Wk,
                                            const float* __restrict__ bk,
                                            const float* __restrict__ Wq,
                                            const float* __restrict__ bq,
                                            float* __restrict__ KQ) {
    __shared__ float As[D_][65];   // k-major, +1 pad
    __shared__ float Bs[D_][65];
    const int m0 = blockIdx.x * 64;
    const int n0 = blockIdx.y * 64;
    const int tid = threadIdx.x;

    const float* Ab = pooled + (size_t)m0 * D_;
    for (int i = tid; i < 64 * D_; i += 256) {
        int r = i / D_, k = i - r * D_;
        As[k][r] = Ab[i];
    }
    const float* Wb = (n0 < E_) ? (Wk + (size_t)n0 * D_) : (Wq + (size_t)(n0 - E_) * D_);
    for (int i = tid; i < 64 * D_; i += 256) {
        int r = i / D_, k = i - r * D_;
        Bs[k][r] = Wb[i];
    }
    __syncthreads();

    const int tm = (tid >> 4) * 4;
    const int tn = (tid & 15) * 4;
    float acc[4][4] = {};
    for (int k = 0; k < D_; ++k) {
        float a[4], b[4];
        #pragma unroll
        for (int i = 0; i < 4; ++i) a[i] = As[k][tm + i];
        #pragma unroll
        for (int j = 0; j < 4; ++j) b[j] = Bs[k][tn + j];
        #pragma unroll
        for (int i = 0; i < 4; ++i)
            #pragma unroll
            for (int j = 0; j < 4; ++j)
                acc[i][j] = fmaf(a[i], b[j], acc[i][j]);
    }
    #pragma unroll
    for (int i = 0; i < 4; ++i)
        #pragma unroll
        for (int j = 0; j < 4; ++j) {
            int n = n0 + tn + j;
            float bias = (n < E_) ? bk[n] : bq[n - E_];
            KQ[(size_t)(m0 + tm + i) * 512 + n] = acc[i][j] + bias;
        }
}

// ---------------- K3: per-batch S = key @ query^T, scaled by 1/16 -----------
__global__ __launch_bounds__(256) void k_scores(const float* __restrict__ KQ,
                                                float* __restrict__ S) {
    __shared__ float As[64][68];
    __shared__ float Bs[64][68];
    const int b  = blockIdx.z;
    const int f0 = blockIdx.x * 64;
    const int g0 = blockIdx.y * 64;
    const float* Ab = KQ + ((size_t)b * F_ + f0) * 512;
    const float* Bb = KQ + ((size_t)b * F_ + g0) * 512 + E_;
    const int tid = threadIdx.x;
    const int tm = (tid >> 4) * 4;
    const int tn = (tid & 15) * 4;
    float acc[4][4] = {};
    for (int ks = 0; ks < E_; ks += 64) {
        for (int i = tid; i < 64 * 64; i += 256) {
            int r = i >> 6, kk = i & 63;
            As[kk][r] = Ab[(size_t)r * 512 + ks + kk];
            Bs[kk][r] = Bb[(size_t)r * 512 + ks + kk];
        }
        __syncthreads();
        #pragma unroll 16
        for (int k = 0; k < 64; ++k) {
            float4 a4 = *(const float4*)(&As[k][tm]);
            float4 b4 = *(const float4*)(&Bs[k][tn]);
            float a[4] = {a4.x, a4.y, a4.z, a4.w};
            float b[4] = {b4.x, b4.y, b4.z, b4.w};
            #pragma unroll
            for (int i = 0; i < 4; ++i)
                #pragma unroll
                for (int j = 0; j < 4; ++j)
                    acc[i][j] = fmaf(a[i], b[j], acc[i][j]);
        }
        __syncthreads();
    }
    float* Sb = S + ((size_t)b * F_ + f0) * 512 + g0;
    #pragma unroll
    for (int i = 0; i < 4; ++i)
        #pragma unroll
        for (int j = 0; j < 4; ++j)
            Sb[(size_t)(tm + i) * 512 + tn + j] = acc[i][j] * (1.0f/16.0f);
}

// ---------------- K4: softmax over g + fw = att @ xmean ---------------------
// One wave per row; pure shuffle reductions, zero __syncthreads.
__global__ __launch_bounds__(256) void k_softmax_fw(const float* __restrict__ S,
                                                    const float* __restrict__ xmean,
                                                    float* __restrict__ fw) {
    const int row  = blockIdx.x * 4 + (threadIdx.x >> 6);
    const int lane = threadIdx.x & 63;
    const int b    = row >> 9;
    const float4* Sr = (const float4*)(S + (size_t)row * 512);
    const float4* xm = (const float4*)(xmean + ((size_t)b << 9));
    float4 v0 = Sr[lane * 2], v1 = Sr[lane * 2 + 1];
    float m = fmaxf(fmaxf(fmaxf(v0.x, v0.y), fmaxf(v0.z, v0.w)),
                    fmaxf(fmaxf(v1.x, v1.y), fmaxf(v1.z, v1.w)));
    #pragma unroll
    for (int off = 32; off; off >>= 1) m = fmaxf(m, __shfl_xor(m, off));
    float4 x0 = xm[lane * 2], x1 = xm[lane * 2 + 1];
    float sum = 0.f, dot = 0.f, p;
    p = expf(v0.x - m); sum += p; dot += p * x0.x;
    p = expf(v0.y - m); sum += p; dot += p * x0.y;
    p = expf(v0.z - m); sum += p; dot += p * x0.z;
    p = expf(v0.w - m); sum += p; dot += p * x0.w;
    p = expf(v1.x - m); sum += p; dot += p * x1.x;
    p = expf(v1.y - m); sum += p; dot += p * x1.y;
    p = expf(v1.z - m); sum += p; dot += p * x1.z;
    p = expf(v1.w - m); sum += p; dot += p * x1.w;
    #pragma unroll
    for (int off = 32; off; off >>= 1) {
        sum += __shfl_xor(sum, off);
        dot += __shfl_xor(dot, off);
    }
    if (lane == 0) fw[row] = dot / sum;
}

// ---------------- K5: per-batch min/max normalize ---------------------------
__global__ __launch_bounds__(512) void k_norm(const float* __restrict__ fw,
                                              float* __restrict__ fwn) {
    __shared__ float rmin[512];
    __shared__ float rmax[512];
    const int b = blockIdx.x, tid = threadIdx.x;
    float v = fw[b * F_ + tid];
    rmin[tid] = v; rmax[tid] = v;
    __syncthreads();
    for (int s = 256; s > 0; s >>= 1) {
        if (tid < s) {
            rmin[tid] = fminf(rmin[tid], rmin[tid + s]);
            rmax[tid] = fmaxf(rmax[tid], rmax[tid + s]);
        }
        __syncthreads();
    }
    float mi = rmin[0], ma = rmax[0];
    fwn[b * F_ + tid] = (v - mi) / (ma - mi) + 1e-6f;
}

// ---------------- K6: out = x * fw_n ---------------------------------------
__global__ __launch_bounds__(256) void k_scale(const float* __restrict__ x,
                                               const float* __restrict__ fwn,
                                               float* __restrict__ out) {
    const int row = blockIdx.x;
    const float s = fwn[row];
    const float4* xr = (const float4*)(x + (size_t)row * T_);
    float4* orow = (float4*)(out + (size_t)row * T_);
    for (int i = threadIdx.x; i < T_/4; i += 256) {
        float4 v = xr[i];
        v.x *= s; v.y *= s; v.z *= s; v.w *= s;
        orow[i] = v;
    }
}

extern "C" void kernel_launch(void* const* d_in, const int* in_sizes, int n_in,
                              void* d_out, int out_size, void* d_ws, size_t ws_size,
                              hipStream_t stream) {
    const float* x  = (const float*)d_in[0];
    const float* Wk = (const float*)d_in[1];
    const float* bk = (const float*)d_in[2];
    const float* Wq = (const float*)d_in[3];
    const float* bq = (const float*)d_in[4];
    float* out = (float*)d_out;

    float* ws     = (float*)d_ws;
    float* pooled = ws;                                  // 8192*100
    float* xmean  = pooled + (size_t)ROWS * D_;          // 8192
    float* KQ     = xmean + ROWS;                        // 8192*512
    float* S      = KQ + (size_t)ROWS * 512;             // 16*512*512
    float* fw     = S + (size_t)B_ * F_ * F_;            // 8192
    float* fwn    = fw + ROWS;                           // 8192

    k_pool<<<ROWS, 256, 0, stream>>>(x, pooled, xmean);
    k_kq<<<dim3(ROWS/64, 512/64), 256, 0, stream>>>(pooled, Wk, bk, Wq, bq, KQ);
    k_scores<<<dim3(F_/64, F_/64, B_), 256, 0, stream>>>(KQ, S);
    k_softmax_fw<<<ROWS/4, 256, 0, stream>>>(S, xmean, fw);
    k_norm<<<B_, 512, 0, stream>>>(fw, fwn);
    k_scale<<<ROWS, 256, 0, stream>>>(x, fwn, out);
}

// Round 3
// 316.017 us; speedup vs baseline: 1.0439x; 1.0159x over previous
//
#include <hip/hip_runtime.h>
#include <hip/hip_bf16.h>
#include <math.h>

#define B_ 16
#define F_ 512
#define T_ 4000
#define D_ 100    // pooled length
#define E_ 256    // embed dim
#define ROWS (B_*F_)   // 8192

typedef __attribute__((ext_vector_type(8))) short short8;
typedef __attribute__((ext_vector_type(4))) float f32x4;

// ---------------- K1: adaptive avg pool (window=40) + per-row mean ----------
// Coalesced float4 global->LDS staging; window sums via b128 LDS reads.
__global__ __launch_bounds__(256) void k_pool(const float* __restrict__ x,
                                              float* __restrict__ pooled,
                                              float* __restrict__ xmean) {
    __shared__ float buf[T_];
    __shared__ float part[4];
    const int row = blockIdx.x;
    const int tid = threadIdx.x;
    const float4* xr = (const float4*)(x + (size_t)row * T_);
    float4* b4 = (float4*)buf;
    for (int i = tid; i < T_/4; i += 256) b4[i] = xr[i];
    __syncthreads();
    float s = 0.f;
    if (tid < 200) {
        const float4* p = (const float4*)(buf + 20 * tid);  // 80B-aligned
        float4 a0 = p[0], a1 = p[1], a2 = p[2], a3 = p[3], a4 = p[4];
        s  = a0.x + a0.y + a0.z + a0.w;
        s += a1.x + a1.y + a1.z + a1.w;
        s += a2.x + a2.y + a2.z + a2.w;
        s += a3.x + a3.y + a3.z + a3.w;
        s += a4.x + a4.y + a4.z + a4.w;
    }
    float other = __shfl_xor(s, 1);
    if (tid < 200 && (tid & 1) == 0)
        pooled[(size_t)row * D_ + (tid >> 1)] = (s + other) * (1.0f/40.0f);
    float tot = s;
    #pragma unroll
    for (int off = 32; off; off >>= 1) tot += __shfl_xor(tot, off);
    if ((tid & 63) == 0) part[tid >> 6] = tot;
    __syncthreads();
    if (tid == 0)
        xmean[row] = (part[0] + part[1] + part[2] + part[3]) * (1.0f/(float)T_);
}

// ---------------- K2: key/query GEMM -> split-bf16 fragments ----------------
// Writes Khi/Klo/Qhi/Qlo in MFMA 16x16x32 fragment order:
// idx = ((b*32 + f/16)*32 + e/8)*128 + (f%16)*8 + (e%8)
// so k_scores' wave loads are contiguous 1KB blocks (lane*16B).
__global__ __launch_bounds__(256) void k_kq(const float* __restrict__ pooled,
                                            const float* __restrict__ Wk,
                                            const float* __restrict__ bk,
                                            const float* __restrict__ Wq,
                                            const float* __restrict__ bq,
                                            short* __restrict__ Khi,
                                            short* __restrict__ Klo,
                                            short* __restrict__ Qhi,
                                            short* __restrict__ Qlo) {
    __shared__ float As[D_][65];   // k-major, +1 pad
    __shared__ float Bs[D_][65];
    const int m0 = blockIdx.x * 64;
    const int n0 = blockIdx.y * 64;
    const int tid = threadIdx.x;

    const float* Ab = pooled + (size_t)m0 * D_;
    for (int i = tid; i < 64 * D_; i += 256) {
        int r = i / D_, k = i - r * D_;
        As[k][r] = Ab[i];
    }
    const float* Wb = (n0 < E_) ? (Wk + (size_t)n0 * D_) : (Wq + (size_t)(n0 - E_) * D_);
    for (int i = tid; i < 64 * D_; i += 256) {
        int r = i / D_, k = i - r * D_;
        Bs[k][r] = Wb[i];
    }
    __syncthreads();

    const int tm = (tid >> 4) * 4;
    const int tn = (tid & 15) * 4;
    float acc[4][4] = {};
    for (int k = 0; k < D_; ++k) {
        float a[4], b[4];
        #pragma unroll
        for (int i = 0; i < 4; ++i) a[i] = As[k][tm + i];
        #pragma unroll
        for (int j = 0; j < 4; ++j) b[j] = Bs[k][tn + j];
        #pragma unroll
        for (int i = 0; i < 4; ++i)
            #pragma unroll
            for (int j = 0; j < 4; ++j)
                acc[i][j] = fmaf(a[i], b[j], acc[i][j]);
    }
    const bool is_key = (n0 < E_);   // block-uniform (n0 multiple of 64)
    short* __restrict__ Phi = is_key ? Khi : Qhi;
    short* __restrict__ Plo = is_key ? Klo : Qlo;
    #pragma unroll
    for (int i = 0; i < 4; ++i)
        #pragma unroll
        for (int jj = 0; jj < 4; ++jj) {
            int n = n0 + tn + jj;
            float bias = is_key ? bk[n] : bq[n - E_];
            float val = acc[i][jj] + bias;
            int mg = m0 + tm + i;
            int b = mg >> 9, f = mg & 511;
            int e = is_key ? n : (n - E_);
            size_t idx = (((size_t)b * 32 + (f >> 4)) * 32 + (e >> 3)) * 128
                       + (size_t)(f & 15) * 8 + (e & 7);
            __hip_bfloat16 h = __float2bfloat16(val);
            float hf = __bfloat162float(h);
            __hip_bfloat16 l = __float2bfloat16(val - hf);
            Phi[idx] = *(short*)&h;
            Plo[idx] = *(short*)&l;
        }
}

// ---------------- K3: S = key @ query^T via split-bf16 MFMA -----------------
// S ~= hi*hi + hi*lo + lo*hi (fp32-accurate). No LDS; fragment loads are
// wave-contiguous 1KB global reads (L1/L2-resident, 8x reuse).
__global__ __launch_bounds__(256) void k_scores(const short* __restrict__ Khi,
                                                const short* __restrict__ Klo,
                                                const short* __restrict__ Qhi,
                                                const short* __restrict__ Qlo,
                                                float* __restrict__ S) {
    const int b    = blockIdx.z;
    const int f0   = blockIdx.x * 64;
    const int g0   = blockIdx.y * 64;
    const int w    = threadIdx.x >> 6;   // wave 0..3 -> g-tile
    const int lane = threadIdx.x & 63;
    const int gt   = (g0 >> 4) + w;
    const size_t qbase = (((size_t)b * 32 + gt) << 12) + (size_t)lane * 8;
    const size_t abase = (((size_t)b * 32 + (f0 >> 4)) << 12) + (size_t)lane * 8;
    f32x4 acc[4] = {};
    #pragma unroll
    for (int s = 0; s < 8; ++s) {
        short8 bh = *(const short8*)(Qhi + qbase + s * 512);
        short8 bl = *(const short8*)(Qlo + qbase + s * 512);
        #pragma unroll
        for (int mt = 0; mt < 4; ++mt) {
            short8 ah = *(const short8*)(Khi + abase + mt * 4096 + s * 512);
            short8 al = *(const short8*)(Klo + abase + mt * 4096 + s * 512);
            acc[mt] = __builtin_amdgcn_mfma_f32_16x16x32_bf16(ah, bh, acc[mt], 0, 0, 0);
            acc[mt] = __builtin_amdgcn_mfma_f32_16x16x32_bf16(ah, bl, acc[mt], 0, 0, 0);
            acc[mt] = __builtin_amdgcn_mfma_f32_16x16x32_bf16(al, bh, acc[mt], 0, 0, 0);
        }
    }
    // C/D layout: col = lane&15, row = (lane>>4)*4 + reg
    const int col = lane & 15, quad = lane >> 4;
    float* Sb = S + ((size_t)b * F_ + f0) * 512 + g0 + w * 16 + col;
    #pragma unroll
    for (int mt = 0; mt < 4; ++mt)
        #pragma unroll
        for (int r = 0; r < 4; ++r)
            Sb[(size_t)(mt * 16 + quad * 4 + r) * 512] = acc[mt][r] * (1.0f/16.0f);
}

// ---------------- K4: softmax over g + fw = att @ xmean ---------------------
__global__ __launch_bounds__(256) void k_softmax_fw(const float* __restrict__ S,
                                                    const float* __restrict__ xmean,
                                                    float* __restrict__ fw) {
    const int row  = blockIdx.x * 4 + (threadIdx.x >> 6);
    const int lane = threadIdx.x & 63;
    const int b    = row >> 9;
    const float4* Sr = (const float4*)(S + (size_t)row * 512);
    const float4* xm = (const float4*)(xmean + ((size_t)b << 9));
    float4 v0 = Sr[lane * 2], v1 = Sr[lane * 2 + 1];
    float m = fmaxf(fmaxf(fmaxf(v0.x, v0.y), fmaxf(v0.z, v0.w)),
                    fmaxf(fmaxf(v1.x, v1.y), fmaxf(v1.z, v1.w)));
    #pragma unroll
    for (int off = 32; off; off >>= 1) m = fmaxf(m, __shfl_xor(m, off));
    float4 x0 = xm[lane * 2], x1 = xm[lane * 2 + 1];
    float sum = 0.f, dot = 0.f, p;
    p = expf(v0.x - m); sum += p; dot += p * x0.x;
    p = expf(v0.y - m); sum += p; dot += p * x0.y;
    p = expf(v0.z - m); sum += p; dot += p * x0.z;
    p = expf(v0.w - m); sum += p; dot += p * x0.w;
    p = expf(v1.x - m); sum += p; dot += p * x1.x;
    p = expf(v1.y - m); sum += p; dot += p * x1.y;
    p = expf(v1.z - m); sum += p; dot += p * x1.z;
    p = expf(v1.w - m); sum += p; dot += p * x1.w;
    #pragma unroll
    for (int off = 32; off; off >>= 1) {
        sum += __shfl_xor(sum, off);
        dot += __shfl_xor(dot, off);
    }
    if (lane == 0) fw[row] = dot / sum;
}

// ---------------- K5: per-batch min/max normalize ---------------------------
__global__ __launch_bounds__(512) void k_norm(const float* __restrict__ fw,
                                              float* __restrict__ fwn) {
    __shared__ float rmin[512];
    __shared__ float rmax[512];
    const int b = blockIdx.x, tid = threadIdx.x;
    float v = fw[b * F_ + tid];
    rmin[tid] = v; rmax[tid] = v;
    __syncthreads();
    for (int s = 256; s > 0; s >>= 1) {
        if (tid < s) {
            rmin[tid] = fminf(rmin[tid], rmin[tid + s]);
            rmax[tid] = fmaxf(rmax[tid], rmax[tid + s]);
        }
        __syncthreads();
    }
    float mi = rmin[0], ma = rmax[0];
    fwn[b * F_ + tid] = (v - mi) / (ma - mi) + 1e-6f;
}

// ---------------- K6: out = x * fw_n ---------------------------------------
__global__ __launch_bounds__(256) void k_scale(const float* __restrict__ x,
                                               const float* __restrict__ fwn,
                                               float* __restrict__ out) {
    const int row = blockIdx.x;
    const float s = fwn[row];
    const float4* xr = (const float4*)(x + (size_t)row * T_);
    float4* orow = (float4*)(out + (size_t)row * T_);
    for (int i = threadIdx.x; i < T_/4; i += 256) {
        float4 v = xr[i];
        v.x *= s; v.y *= s; v.z *= s; v.w *= s;
        orow[i] = v;
    }
}

extern "C" void kernel_launch(void* const* d_in, const int* in_sizes, int n_in,
                              void* d_out, int out_size, void* d_ws, size_t ws_size,
                              hipStream_t stream) {
    const float* x  = (const float*)d_in[0];
    const float* Wk = (const float*)d_in[1];
    const float* bk = (const float*)d_in[2];
    const float* Wq = (const float*)d_in[3];
    const float* bq = (const float*)d_in[4];
    float* out = (float*)d_out;

    float* ws     = (float*)d_ws;
    float* pooled = ws;                                  // 8192*100 f32
    float* xmean  = pooled + (size_t)ROWS * D_;          // 8192 f32
    float* S      = xmean + ROWS;                        // 16*512*512 f32
    float* fw     = S + (size_t)B_ * F_ * F_;            // 8192 f32
    float* fwn    = fw + ROWS;                           // 8192 f32
    short* Khi    = (short*)(fwn + ROWS);                // 16*32*4096 bf16 bits
    short* Klo    = Khi + (size_t)B_ * 32 * 4096;
    short* Qhi    = Klo + (size_t)B_ * 32 * 4096;
    short* Qlo    = Qhi + (size_t)B_ * 32 * 4096;

    k_pool<<<ROWS, 256, 0, stream>>>(x, pooled, xmean);
    k_kq<<<dim3(ROWS/64, 512/64), 256, 0, stream>>>(pooled, Wk, bk, Wq, bq,
                                                    Khi, Klo, Qhi, Qlo);
    k_scores<<<dim3(F_/64, F_/64, B_), 256, 0, stream>>>(Khi, Klo, Qhi, Qlo, S);
    k_softmax_fw<<<ROWS/4, 256, 0, stream>>>(S, xmean, fw);
    k_norm<<<B_, 512, 0, stream>>>(fw, fwn);
    k_scale<<<ROWS, 256, 0, stream>>>(x, fwn, out);
}